// Round 25
// baseline (724.658 us; speedup 1.0000x reference)
//
#include <hip/hip_runtime.h>
#include <stdint.h>

#define CDIM 256
#define NCLS 200
#define NSEL 128
#define SEQ  4096
#define RPB  16      // rows per score-block
#define CCH  32      // einsum chunk (fixed by bitwise semantics)

// ---------------------------------------------------------------------------
// numpy dispatched f32 exp, fused-quadrant rational path (VERIFIED bitwise
// vs harness reference in rounds 19-24 -- do not alter any operation).
// ---------------------------------------------------------------------------
__device__ __forceinline__ float np_expf(float x) {
    const float LOG2E = 1.442695040888963407359924681001892137f;
    const float MAGIC = 12582912.0f;
    const float CW_HI = -6.93145752e-1f;
    const float CW_LO = -1.42860677e-6f;

    float q = __fsub_rn(__fmaf_rn(x, LOG2E, MAGIC), MAGIC);

    float y = __fmaf_rn(q, CW_HI, x);
    y = __fmaf_rn(q, CW_LO, y);

    float num = __fmaf_rn(5.082762527590693718096e-04f, y,
                          6.757896990527504603057e-03f);
    num = __fmaf_rn(num, y, 5.114512081637298353406e-02f);
    num = __fmaf_rn(num, y, 2.473615434895520810817e-01f);
    num = __fmaf_rn(num, y, 7.257664613233124478488e-01f);
    num = __fmaf_rn(num, y, 9.999999999980870924916e-01f);

    float den = __fmaf_rn(2.159509375685829852307e-02f, y,
                          -2.742335390411667452936e-01f);
    den = __fmaf_rn(den, y, 1.0f);

    const float r = __fdiv_rn(num, den);
    return ldexpf(r, (int)q);
}

// async global->LDS 16B per lane; LDS dest = wave-uniform base + lane*16
static __device__ __forceinline__ void gl_lds16(const float* g, float* lds_base) {
    __builtin_amdgcn_global_load_lds(
        (const __attribute__((address_space(1))) void*)g,
        (__attribute__((address_space(3))) void*)lds_base, 16, 0, 0);
}

// ---------------------------------------------------------------------------
// Score kernel: bitwise-identical arithmetic to rounds 19-24 PASS.
// Structure: rg = wave id (x reads wave-uniform -> L1 broadcast / s_load;
// no xs LDS tile), q = lane (W LDS reads lane-contiguous, conflict-free).
// W double-buffered in LDS via async global_load_lds (one barrier/chunk).
// LDS = 2 x 25.6 KB (buffer 0 reused as lg) + ~1.2 KB => 3 blocks/CU.
// ---------------------------------------------------------------------------
__global__ __launch_bounds__(256, 3) void score_kernel(
    const float* __restrict__ x, const float* __restrict__ W,
    const float* __restrict__ bias, float* __restrict__ scores)
{
    __shared__ __align__(16) float wt[2][CCH * NCLS];   // 51.2 KB
    __shared__ float mx[RPB][16];
    __shared__ float sp[RPB][16];
    __shared__ float mrow[RPB];

    const int tid  = threadIdx.x;
    const int wid  = tid >> 6;
    const int lane = tid & 63;
    const long long row0 = (long long)blockIdx.x * RPB;

    // async stage W chunk 0 (1600 float4 = 25 wave-tiles over 4 waves)
    for (int t = wid; t < CCH * NCLS / 256; t += 4)
        gl_lds16(W + (t * 64 + lane) * 4, &wt[0][t * 256]);
    __syncthreads();                           // vmcnt(0) drain -> landed

    const int rgu = __builtin_amdgcn_readfirstlane(wid);  // uniform row group
    const int q   = (lane < 50) ? lane : 49;   // clamped; lanes>=50 discarded
    const float* xbase = x + (row0 + rgu * 4) * CDIM;     // uniform pointer

    float acc[4][4][8];                        // [row][class][chain-lane]
    #pragma unroll
    for (int r = 0; r < 4; ++r)
        #pragma unroll
        for (int k = 0; k < 4; ++k)
            #pragma unroll
            for (int j = 0; j < 8; ++j) acc[r][k][j] = 0.0f;

    for (int c8 = 0; c8 < CDIM / CCH; ++c8) {  // 8 chunks, ascending
        const int cur = c8 & 1;
        if (c8 < CDIM / CCH - 1) {             // async prefetch next chunk
            const float* wg = W + (long long)(c8 + 1) * CCH * NCLS;
            for (int t = wid; t < CCH * NCLS / 256; t += 4)
                gl_lds16(wg + (t * 64 + lane) * 4, &wt[cur ^ 1][t * 256]);
        }

        const float* wtc = wt[cur];
        const int cc = c8 * CCH;
        #pragma unroll
        for (int i = 3; i >= 0; --i) {         // reversed sub-vectors (exact)
            float4 xq0[4], xq1[4];
            #pragma unroll
            for (int r = 0; r < 4; ++r) {      // wave-uniform x (L1 broadcast)
                const float* xrow = xbase + r * CDIM + cc + 8 * i;
                xq0[r] = *reinterpret_cast<const float4*>(xrow);
                xq1[r] = *reinterpret_cast<const float4*>(xrow + 4);
            }
            #pragma unroll
            for (int j = 0; j < 8; ++j) {
                const float4 wv = *reinterpret_cast<const float4*>(
                    &wtc[(8 * i + j) * NCLS + 4 * q]);
                #pragma unroll
                for (int r = 0; r < 4; ++r) {
                    const float xv = (j < 4)
                        ? reinterpret_cast<const float*>(&xq0[r])[j]
                        : reinterpret_cast<const float*>(&xq1[r])[j - 4];
                    acc[r][0][j] = __fmaf_rn(xv, wv.x, acc[r][0][j]);
                    acc[r][1][j] = __fmaf_rn(xv, wv.y, acc[r][1][j]);
                    acc[r][2][j] = __fmaf_rn(xv, wv.z, acc[r][2][j]);
                    acc[r][3][j] = __fmaf_rn(xv, wv.w, acc[r][3][j]);
                }
            }
        }
        __syncthreads();   // reads of wt[cur] done; prefetch landed
    }

    float* lg = wt[0];     // chunk 7 consumed wt[1]; wt[0] free -> lg[16][200]

    if (lane < 50) {
        const float4 bq = reinterpret_cast<const float4*>(bias)[q];
        const float bv[4] = { bq.x, bq.y, bq.z, bq.w };
        #pragma unroll
        for (int r = 0; r < 4; ++r) {
            float h[4];
            #pragma unroll
            for (int k = 0; k < 4; ++k) {
                const float* a = acc[r][k];
                h[k] = __fadd_rn(
                    __fadd_rn(__fadd_rn(a[0], a[1]), __fadd_rn(a[2], a[3])),
                    __fadd_rn(__fadd_rn(a[4], a[5]), __fadd_rn(a[6], a[7])));
                h[k] = __fadd_rn(h[k], bv[k]);        // b==0: exact no-op
            }
            *reinterpret_cast<float4*>(&lg[(rgu * 4 + r) * NCLS + 4 * q]) =
                make_float4(h[0], h[1], h[2], h[3]);
        }
    }
    __syncthreads();

    // ---- row max: 16 rows x 16 slots, fmax tree (bitwise-safe) ----
    {
        const int r = tid >> 4, l = tid & 15;
        float mv = lg[r * NCLS + l];
        for (int n = l + 16; n < NCLS; n += 16) mv = fmaxf(mv, lg[r * NCLS + n]);
        mx[r][l] = mv;
    }
    __syncthreads();
    if (tid < RPB) {
        float mv = mx[tid][0];
        #pragma unroll
        for (int l = 1; l < 16; ++l) mv = fmaxf(mv, mx[tid][l]);
        mrow[tid] = mv;
    }
    __syncthreads();

    // ---- exp: elementwise, parallel ----
    for (int i = tid; i < RPB * NCLS; i += 256) {
        const int r = i / NCLS;
        lg[i] = np_expf(__fsub_rn(lg[i], mrow[r]));
    }
    __syncthreads();

    // ---- pairwise sum: 8 chains x 2 blocks x 16 rows = 256 threads ----
    {
        const int r = tid >> 4, sub = tid & 15;
        const int k = sub & 7, blk = sub >> 3;
        const float* a = &lg[r * NCLS + (blk ? 96 : 0)];
        const int len = blk ? 104 : 96;
        float c = a[k];
        for (int i = 8; i < len; i += 8) c = __fadd_rn(c, a[i + k]);
        sp[r][blk * 8 + k] = c;
    }
    __syncthreads();

    if (tid < RPB) {
        const float* p = sp[tid];
        const float s1 =
            __fadd_rn(__fadd_rn(__fadd_rn(p[0], p[1]), __fadd_rn(p[2], p[3])),
                      __fadd_rn(__fadd_rn(p[4], p[5]), __fadd_rn(p[6], p[7])));
        const float s2 =
            __fadd_rn(__fadd_rn(__fadd_rn(p[8], p[9]), __fadd_rn(p[10], p[11])),
                      __fadd_rn(__fadd_rn(p[12], p[13]), __fadd_rn(p[14], p[15])));
        const float S = __fadd_rn(s1, s2);
        scores[row0 + tid] = __fdiv_rn(1.0f, S);   // emax == 1.0f exactly
    }
}

// ---------------------------------------------------------------------------
// Kernel 2: per batch, sort 4096 packed keys desc (stable, smaller index
// first on ties), gather top-128 rows in rank order. (Unchanged from PASS.)
// ---------------------------------------------------------------------------
__global__ __launch_bounds__(256) void sort_gather_kernel(
    const float* __restrict__ pmax, const float* __restrict__ x,
    float* __restrict__ out)
{
    __shared__ uint64_t K[SEQ];   // 32 KB

    const int tid = threadIdx.x;
    const int b   = blockIdx.x;

    for (int i = tid; i < SEQ; i += 256) {
        const uint32_t pb = __float_as_uint(pmax[(long long)b * SEQ + i]);
        K[i] = ((uint64_t)pb << 12) | (uint64_t)(SEQ - 1 - i);
    }
    __syncthreads();

    for (int k = 2; k <= SEQ; k <<= 1) {
        for (int j = k >> 1; j > 0; j >>= 1) {
            for (int t = tid; t < SEQ / 2; t += 256) {
                const int i = ((t & ~(j - 1)) << 1) | (t & (j - 1));
                const int p = i | j;
                const bool desc = ((i & k) == 0);
                const uint64_t a = K[i], c = K[p];
                const bool sw = desc ? (a < c) : (a > c);
                if (sw) { K[i] = c; K[p] = a; }
            }
            __syncthreads();
        }
    }

    const float4* x4   = reinterpret_cast<const float4*>(x);
    float4*       out4 = reinterpret_cast<float4*>(out);
    for (int t = tid; t < NSEL * (CDIM / 4); t += 256) {
        const int jj = t >> 6;
        const int c4 = t & 63;
        const int idx = (SEQ - 1) - (int)(K[jj] & (uint64_t)(SEQ - 1));
        out4[((long long)b * NSEL + jj) * (CDIM / 4) + c4] =
            x4[((long long)b * SEQ + idx) * (CDIM / 4) + c4];
    }
}

extern "C" void kernel_launch(void* const* d_in, const int* in_sizes, int n_in,
                              void* d_out, int out_size, void* d_ws, size_t ws_size,
                              hipStream_t stream) {
    const float* x    = (const float*)d_in[0];
    const float* W    = (const float*)d_in[1];
    const float* bias = (const float*)d_in[2];
    float* out   = (float*)d_out;
    float* score = (float*)d_ws;                     // 131072 * 4 B = 512 KB

    const long long nrows = (long long)in_sizes[0] / CDIM;   // B*S
    const int B = out_size / (NSEL * CDIM);                  // 32

    score_kernel<<<(int)(nrows / RPB), 256, 0, stream>>>(x, W, bias, score);
    sort_gather_kernel<<<B, 256, 0, stream>>>(score, x, out);
}

// Round 26
// 458.652 us; speedup vs baseline: 1.5800x; 1.5800x over previous
//
#include <hip/hip_runtime.h>
#include <stdint.h>

#define CDIM 256
#define NCLS 200
#define NSEL 128
#define SEQ  4096
#define RPB  16      // rows per score-block
#define CCH  32      // einsum chunk (fixed by bitwise semantics)

// ---------------------------------------------------------------------------
// numpy dispatched f32 exp, fused-quadrant rational path (VERIFIED bitwise
// vs harness reference in rounds 19-25 -- do not alter any operation).
// ---------------------------------------------------------------------------
__device__ __forceinline__ float np_expf(float x) {
    const float LOG2E = 1.442695040888963407359924681001892137f;
    const float MAGIC = 12582912.0f;
    const float CW_HI = -6.93145752e-1f;
    const float CW_LO = -1.42860677e-6f;

    float q = __fsub_rn(__fmaf_rn(x, LOG2E, MAGIC), MAGIC);

    float y = __fmaf_rn(q, CW_HI, x);
    y = __fmaf_rn(q, CW_LO, y);

    float num = __fmaf_rn(5.082762527590693718096e-04f, y,
                          6.757896990527504603057e-03f);
    num = __fmaf_rn(num, y, 5.114512081637298353406e-02f);
    num = __fmaf_rn(num, y, 2.473615434895520810817e-01f);
    num = __fmaf_rn(num, y, 7.257664613233124478488e-01f);
    num = __fmaf_rn(num, y, 9.999999999980870924916e-01f);

    float den = __fmaf_rn(2.159509375685829852307e-02f, y,
                          -2.742335390411667452936e-01f);
    den = __fmaf_rn(den, y, 1.0f);

    const float r = __fdiv_rn(num, den);
    return ldexpf(r, (int)q);
}

// ---------------------------------------------------------------------------
// Score kernel: bitwise-identical arithmetic to rounds 19-25 PASS.
// Structure (r21 + proven deltas):
//  - W staged in LDS single-buffer, r21's exact float4 staging, 2 barriers/chunk
//  - rg = wave id in SGPR -> x reads are wave-uniform scalar s_loads from
//    global (no xs LDS tile, no x VGPR traffic)
//  - q = lane (W LDS reads lane-contiguous b128)
//  - NO __launch_bounds__ waves hint (r25 lesson: it forced acc spills)
// LDS = 25.6 (wt) + 12.8 (lg) + ~1.2 KB.
// ---------------------------------------------------------------------------
__global__ __launch_bounds__(256) void score_kernel(
    const float* __restrict__ x, const float* __restrict__ W,
    const float* __restrict__ bias, float* __restrict__ scores)
{
    __shared__ __align__(16) float wt[CCH * NCLS];    // 25.6 KB
    __shared__ __align__(16) float lg[RPB * NCLS];    // 12.8 KB
    __shared__ float mx[RPB][16];
    __shared__ float sp[RPB][16];
    __shared__ float mrow[RPB];

    const int tid  = threadIdx.x;
    const int wid  = tid >> 6;
    const int lane = tid & 63;
    const long long row0 = (long long)blockIdx.x * RPB;

    const int rgu = __builtin_amdgcn_readfirstlane(wid);   // uniform row group
    const int q   = (lane < 50) ? lane : 49;               // clamped quad
    const float* xbase = x + (row0 + rgu * 4) * CDIM;      // uniform pointer

    float acc[4][4][8];                        // [row][class][chain-lane]
    #pragma unroll
    for (int r = 0; r < 4; ++r)
        #pragma unroll
        for (int k = 0; k < 4; ++k)
            #pragma unroll
            for (int j = 0; j < 8; ++j) acc[r][k][j] = 0.0f;

    for (int c8 = 0; c8 < CDIM / CCH; ++c8) {  // 8 chunks, ascending
        __syncthreads();                        // prev readers done
        {   // stage W chunk (float4, coalesced -- r21's exact pattern)
            const float4* wg = reinterpret_cast<const float4*>(W + c8 * CCH * NCLS);
            float4* wt4 = reinterpret_cast<float4*>(wt);
            for (int i = tid; i < CCH * NCLS / 4; i += 256) wt4[i] = wg[i];
        }
        __syncthreads();                        // chunk landed

        const int cc = c8 * CCH;
        #pragma unroll
        for (int i = 3; i >= 0; --i) {          // reversed sub-vectors (exact)
            // wave-uniform x: scalar loads (s_load), kept in SGPRs
            float xv8[4][8];
            #pragma unroll
            for (int r = 0; r < 4; ++r)
                #pragma unroll
                for (int j = 0; j < 8; ++j)
                    xv8[r][j] = xbase[r * CDIM + cc + 8 * i + j];

            #pragma unroll
            for (int j = 0; j < 8; ++j) {
                const float4 wv = *reinterpret_cast<const float4*>(
                    &wt[(8 * i + j) * NCLS + 4 * q]);
                #pragma unroll
                for (int r = 0; r < 4; ++r) {
                    const float xv = xv8[r][j];
                    acc[r][0][j] = __fmaf_rn(xv, wv.x, acc[r][0][j]);
                    acc[r][1][j] = __fmaf_rn(xv, wv.y, acc[r][1][j]);
                    acc[r][2][j] = __fmaf_rn(xv, wv.z, acc[r][2][j]);
                    acc[r][3][j] = __fmaf_rn(xv, wv.w, acc[r][3][j]);
                }
            }
        }
    }
    __syncthreads();

    if (lane < 50) {
        const float4 bq = reinterpret_cast<const float4*>(bias)[q];
        const float bv[4] = { bq.x, bq.y, bq.z, bq.w };
        #pragma unroll
        for (int r = 0; r < 4; ++r) {
            float h[4];
            #pragma unroll
            for (int k = 0; k < 4; ++k) {
                const float* a = acc[r][k];
                h[k] = __fadd_rn(
                    __fadd_rn(__fadd_rn(a[0], a[1]), __fadd_rn(a[2], a[3])),
                    __fadd_rn(__fadd_rn(a[4], a[5]), __fadd_rn(a[6], a[7])));
                h[k] = __fadd_rn(h[k], bv[k]);        // b==0: exact no-op
            }
            *reinterpret_cast<float4*>(&lg[(rgu * 4 + r) * NCLS + 4 * q]) =
                make_float4(h[0], h[1], h[2], h[3]);
        }
    }
    __syncthreads();

    // ---- row max: 16 rows x 16 slots, fmax tree (bitwise-safe) ----
    {
        const int r = tid >> 4, l = tid & 15;
        float mv = lg[r * NCLS + l];
        for (int n = l + 16; n < NCLS; n += 16) mv = fmaxf(mv, lg[r * NCLS + n]);
        mx[r][l] = mv;
    }
    __syncthreads();
    if (tid < RPB) {
        float mv = mx[tid][0];
        #pragma unroll
        for (int l = 1; l < 16; ++l) mv = fmaxf(mv, mx[tid][l]);
        mrow[tid] = mv;
    }
    __syncthreads();

    // ---- exp: elementwise, parallel ----
    for (int i = tid; i < RPB * NCLS; i += 256) {
        const int r = i / NCLS;
        lg[i] = np_expf(__fsub_rn(lg[i], mrow[r]));
    }
    __syncthreads();

    // ---- pairwise sum: 8 chains x 2 blocks x 16 rows = 256 threads ----
    {
        const int r = tid >> 4, sub = tid & 15;
        const int k = sub & 7, blk = sub >> 3;
        const float* a = &lg[r * NCLS + (blk ? 96 : 0)];
        const int len = blk ? 104 : 96;
        float c = a[k];
        for (int i = 8; i < len; i += 8) c = __fadd_rn(c, a[i + k]);
        sp[r][blk * 8 + k] = c;
    }
    __syncthreads();

    if (tid < RPB) {
        const float* p = sp[tid];
        const float s1 =
            __fadd_rn(__fadd_rn(__fadd_rn(p[0], p[1]), __fadd_rn(p[2], p[3])),
                      __fadd_rn(__fadd_rn(p[4], p[5]), __fadd_rn(p[6], p[7])));
        const float s2 =
            __fadd_rn(__fadd_rn(__fadd_rn(p[8], p[9]), __fadd_rn(p[10], p[11])),
                      __fadd_rn(__fadd_rn(p[12], p[13]), __fadd_rn(p[14], p[15])));
        const float S = __fadd_rn(s1, s2);
        scores[row0 + tid] = __fdiv_rn(1.0f, S);   // emax == 1.0f exactly
    }
}

// ---------------------------------------------------------------------------
// Kernel 2: per batch, sort 4096 packed keys desc (stable, smaller index
// first on ties), gather top-128 rows in rank order. (Unchanged from PASS.)
// ---------------------------------------------------------------------------
__global__ __launch_bounds__(256) void sort_gather_kernel(
    const float* __restrict__ pmax, const float* __restrict__ x,
    float* __restrict__ out)
{
    __shared__ uint64_t K[SEQ];   // 32 KB

    const int tid = threadIdx.x;
    const int b   = blockIdx.x;

    for (int i = tid; i < SEQ; i += 256) {
        const uint32_t pb = __float_as_uint(pmax[(long long)b * SEQ + i]);
        K[i] = ((uint64_t)pb << 12) | (uint64_t)(SEQ - 1 - i);
    }
    __syncthreads();

    for (int k = 2; k <= SEQ; k <<= 1) {
        for (int j = k >> 1; j > 0; j >>= 1) {
            for (int t = tid; t < SEQ / 2; t += 256) {
                const int i = ((t & ~(j - 1)) << 1) | (t & (j - 1));
                const int p = i | j;
                const bool desc = ((i & k) == 0);
                const uint64_t a = K[i], c = K[p];
                const bool sw = desc ? (a < c) : (a > c);
                if (sw) { K[i] = c; K[p] = a; }
            }
            __syncthreads();
        }
    }

    const float4* x4   = reinterpret_cast<const float4*>(x);
    float4*       out4 = reinterpret_cast<float4*>(out);
    for (int t = tid; t < NSEL * (CDIM / 4); t += 256) {
        const int jj = t >> 6;
        const int c4 = t & 63;
        const int idx = (SEQ - 1) - (int)(K[jj] & (uint64_t)(SEQ - 1));
        out4[((long long)b * NSEL + jj) * (CDIM / 4) + c4] =
            x4[((long long)b * SEQ + idx) * (CDIM / 4) + c4];
    }
}

extern "C" void kernel_launch(void* const* d_in, const int* in_sizes, int n_in,
                              void* d_out, int out_size, void* d_ws, size_t ws_size,
                              hipStream_t stream) {
    const float* x    = (const float*)d_in[0];
    const float* W    = (const float*)d_in[1];
    const float* bias = (const float*)d_in[2];
    float* out   = (float*)d_out;
    float* score = (float*)d_ws;                     // 131072 * 4 B = 512 KB

    const long long nrows = (long long)in_sizes[0] / CDIM;   // B*S
    const int B = out_size / (NSEL * CDIM);                  // 32

    score_kernel<<<(int)(nrows / RPB), 256, 0, stream>>>(x, W, bias, score);
    sort_gather_kernel<<<B, 256, 0, stream>>>(score, x, out);
}

// Round 27
// 438.303 us; speedup vs baseline: 1.6533x; 1.0464x over previous
//
#include <hip/hip_runtime.h>
#include <stdint.h>

#define CDIM 256
#define NCLS 200
#define NSEL 128
#define SEQ  4096
#define RPB  16      // rows per score-block
#define CCH  32      // einsum chunk (fixed by bitwise semantics)

// ---------------------------------------------------------------------------
// numpy dispatched f32 exp, fused-quadrant rational path (VERIFIED bitwise
// vs harness reference in rounds 19-26 -- do not alter any operation).
// ---------------------------------------------------------------------------
__device__ __forceinline__ float np_expf(float x) {
    const float LOG2E = 1.442695040888963407359924681001892137f;
    const float MAGIC = 12582912.0f;
    const float CW_HI = -6.93145752e-1f;
    const float CW_LO = -1.42860677e-6f;

    float q = __fsub_rn(__fmaf_rn(x, LOG2E, MAGIC), MAGIC);

    float y = __fmaf_rn(q, CW_HI, x);
    y = __fmaf_rn(q, CW_LO, y);

    float num = __fmaf_rn(5.082762527590693718096e-04f, y,
                          6.757896990527504603057e-03f);
    num = __fmaf_rn(num, y, 5.114512081637298353406e-02f);
    num = __fmaf_rn(num, y, 2.473615434895520810817e-01f);
    num = __fmaf_rn(num, y, 7.257664613233124478488e-01f);
    num = __fmaf_rn(num, y, 9.999999999980870924916e-01f);

    float den = __fmaf_rn(2.159509375685829852307e-02f, y,
                          -2.742335390411667452936e-01f);
    den = __fmaf_rn(den, y, 1.0f);

    const float r = __fdiv_rn(num, den);
    return ldexpf(r, (int)q);
}

// async global->LDS 16B per lane; LDS dest = wave-uniform base + lane*16
static __device__ __forceinline__ void gl_lds16(const float* g, float* lds_base) {
    __builtin_amdgcn_global_load_lds(
        (const __attribute__((address_space(1))) void*)g,
        (__attribute__((address_space(3))) void*)lds_base, 16, 0, 0);
}

// ---------------------------------------------------------------------------
// Score kernel: bitwise-identical arithmetic to rounds 19-26 PASS.
// Structure = r25 WITHOUT the launch_bounds VGPR clamp (r25's sole failure):
//  - W double-buffered in LDS via async global_load_lds, ONE barrier/chunk
//  - no xs tile: rg = wave id (SGPR) -> x reads are wave-uniform s_loads
//  - q = lane (W LDS reads lane-contiguous b128, conflict-light)
//  - lg aliases wt[0] (free after chunk 7 consumes wt[1])
// LDS = 51.2 + ~1.3 KB => 3 blocks/CU.
// ---------------------------------------------------------------------------
__global__ __launch_bounds__(256) void score_kernel(
    const float* __restrict__ x, const float* __restrict__ W,
    const float* __restrict__ bias, float* __restrict__ scores)
{
    __shared__ __align__(16) float wt[2][CCH * NCLS];   // 51.2 KB
    __shared__ float mx[RPB][16];
    __shared__ float sp[RPB][16];
    __shared__ float mrow[RPB];

    const int tid  = threadIdx.x;
    const int wid  = tid >> 6;
    const int lane = tid & 63;
    const long long row0 = (long long)blockIdx.x * RPB;

    // async stage W chunk 0 (1600 float4 = 25 wave-tiles over 4 waves)
    for (int t = wid; t < CCH * NCLS / 256; t += 4)
        gl_lds16(W + (t * 64 + lane) * 4, &wt[0][t * 256]);

    const int rgu = __builtin_amdgcn_readfirstlane(wid);   // uniform row group
    const int q   = (lane < 50) ? lane : 49;               // clamped quad
    const float* xbase = x + (row0 + rgu * 4) * CDIM;      // uniform pointer

    float acc[4][4][8];                        // [row][class][chain-lane]
    #pragma unroll
    for (int r = 0; r < 4; ++r)
        #pragma unroll
        for (int k = 0; k < 4; ++k)
            #pragma unroll
            for (int j = 0; j < 8; ++j) acc[r][k][j] = 0.0f;

    __syncthreads();                           // chunk 0 landed (vmcnt drain)

    for (int c8 = 0; c8 < CDIM / CCH; ++c8) {  // 8 chunks, ascending
        const int cur = c8 & 1;
        if (c8 < CDIM / CCH - 1) {             // async prefetch next chunk
            const float* wg = W + (long long)(c8 + 1) * CCH * NCLS;
            for (int t = wid; t < CCH * NCLS / 256; t += 4)
                gl_lds16(wg + (t * 64 + lane) * 4, &wt[cur ^ 1][t * 256]);
        }

        const float* wtc = wt[cur];
        const int cc = c8 * CCH;
        #pragma unroll
        for (int i = 3; i >= 0; --i) {         // reversed sub-vectors (exact)
            // wave-uniform x: scalar loads, kept in SGPRs
            float xv8[4][8];
            #pragma unroll
            for (int r = 0; r < 4; ++r)
                #pragma unroll
                for (int j = 0; j < 8; ++j)
                    xv8[r][j] = xbase[r * CDIM + cc + 8 * i + j];

            #pragma unroll
            for (int j = 0; j < 8; ++j) {
                const float4 wv = *reinterpret_cast<const float4*>(
                    &wtc[(8 * i + j) * NCLS + 4 * q]);
                #pragma unroll
                for (int r = 0; r < 4; ++r) {
                    const float xv = xv8[r][j];
                    acc[r][0][j] = __fmaf_rn(xv, wv.x, acc[r][0][j]);
                    acc[r][1][j] = __fmaf_rn(xv, wv.y, acc[r][1][j]);
                    acc[r][2][j] = __fmaf_rn(xv, wv.z, acc[r][2][j]);
                    acc[r][3][j] = __fmaf_rn(xv, wv.w, acc[r][3][j]);
                }
            }
        }
        __syncthreads();   // readers of wt[cur] done; prefetch landed
    }

    float* lg = wt[0];     // chunk 7 consumed wt[1]; wt[0] free -> lg[16][200]

    if (lane < 50) {
        const float4 bq = reinterpret_cast<const float4*>(bias)[q];
        const float bv[4] = { bq.x, bq.y, bq.z, bq.w };
        #pragma unroll
        for (int r = 0; r < 4; ++r) {
            float h[4];
            #pragma unroll
            for (int k = 0; k < 4; ++k) {
                const float* a = acc[r][k];
                h[k] = __fadd_rn(
                    __fadd_rn(__fadd_rn(a[0], a[1]), __fadd_rn(a[2], a[3])),
                    __fadd_rn(__fadd_rn(a[4], a[5]), __fadd_rn(a[6], a[7])));
                h[k] = __fadd_rn(h[k], bv[k]);        // b==0: exact no-op
            }
            *reinterpret_cast<float4*>(&lg[(rgu * 4 + r) * NCLS + 4 * q]) =
                make_float4(h[0], h[1], h[2], h[3]);
        }
    }
    __syncthreads();

    // ---- row max: 16 rows x 16 slots, fmax tree (bitwise-safe) ----
    {
        const int r = tid >> 4, l = tid & 15;
        float mv = lg[r * NCLS + l];
        for (int n = l + 16; n < NCLS; n += 16) mv = fmaxf(mv, lg[r * NCLS + n]);
        mx[r][l] = mv;
    }
    __syncthreads();
    if (tid < RPB) {
        float mv = mx[tid][0];
        #pragma unroll
        for (int l = 1; l < 16; ++l) mv = fmaxf(mv, mx[tid][l]);
        mrow[tid] = mv;
    }
    __syncthreads();

    // ---- exp: elementwise, parallel ----
    for (int i = tid; i < RPB * NCLS; i += 256) {
        const int r = i / NCLS;
        lg[i] = np_expf(__fsub_rn(lg[i], mrow[r]));
    }
    __syncthreads();

    // ---- pairwise sum: 8 chains x 2 blocks x 16 rows = 256 threads ----
    {
        const int r = tid >> 4, sub = tid & 15;
        const int k = sub & 7, blk = sub >> 3;
        const float* a = &lg[r * NCLS + (blk ? 96 : 0)];
        const int len = blk ? 104 : 96;
        float c = a[k];
        for (int i = 8; i < len; i += 8) c = __fadd_rn(c, a[i + k]);
        sp[r][blk * 8 + k] = c;
    }
    __syncthreads();

    if (tid < RPB) {
        const float* p = sp[tid];
        const float s1 =
            __fadd_rn(__fadd_rn(__fadd_rn(p[0], p[1]), __fadd_rn(p[2], p[3])),
                      __fadd_rn(__fadd_rn(p[4], p[5]), __fadd_rn(p[6], p[7])));
        const float s2 =
            __fadd_rn(__fadd_rn(__fadd_rn(p[8], p[9]), __fadd_rn(p[10], p[11])),
                      __fadd_rn(__fadd_rn(p[12], p[13]), __fadd_rn(p[14], p[15])));
        const float S = __fadd_rn(s1, s2);
        scores[row0 + tid] = __fdiv_rn(1.0f, S);   // emax == 1.0f exactly
    }
}

// ---------------------------------------------------------------------------
// Kernel 2: per batch, sort 4096 packed keys desc (stable, smaller index
// first on ties), gather top-128 rows in rank order. (Unchanged from PASS.)
// ---------------------------------------------------------------------------
__global__ __launch_bounds__(256) void sort_gather_kernel(
    const float* __restrict__ pmax, const float* __restrict__ x,
    float* __restrict__ out)
{
    __shared__ uint64_t K[SEQ];   // 32 KB

    const int tid = threadIdx.x;
    const int b   = blockIdx.x;

    for (int i = tid; i < SEQ; i += 256) {
        const uint32_t pb = __float_as_uint(pmax[(long long)b * SEQ + i]);
        K[i] = ((uint64_t)pb << 12) | (uint64_t)(SEQ - 1 - i);
    }
    __syncthreads();

    for (int k = 2; k <= SEQ; k <<= 1) {
        for (int j = k >> 1; j > 0; j >>= 1) {
            for (int t = tid; t < SEQ / 2; t += 256) {
                const int i = ((t & ~(j - 1)) << 1) | (t & (j - 1));
                const int p = i | j;
                const bool desc = ((i & k) == 0);
                const uint64_t a = K[i], c = K[p];
                const bool sw = desc ? (a < c) : (a > c);
                if (sw) { K[i] = c; K[p] = a; }
            }
            __syncthreads();
        }
    }

    const float4* x4   = reinterpret_cast<const float4*>(x);
    float4*       out4 = reinterpret_cast<float4*>(out);
    for (int t = tid; t < NSEL * (CDIM / 4); t += 256) {
        const int jj = t >> 6;
        const int c4 = t & 63;
        const int idx = (SEQ - 1) - (int)(K[jj] & (uint64_t)(SEQ - 1));
        out4[((long long)b * NSEL + jj) * (CDIM / 4) + c4] =
            x4[((long long)b * SEQ + idx) * (CDIM / 4) + c4];
    }
}

extern "C" void kernel_launch(void* const* d_in, const int* in_sizes, int n_in,
                              void* d_out, int out_size, void* d_ws, size_t ws_size,
                              hipStream_t stream) {
    const float* x    = (const float*)d_in[0];
    const float* W    = (const float*)d_in[1];
    const float* bias = (const float*)d_in[2];
    float* out   = (float*)d_out;
    float* score = (float*)d_ws;                     // 131072 * 4 B = 512 KB

    const long long nrows = (long long)in_sizes[0] / CDIM;   // B*S
    const int B = out_size / (NSEL * CDIM);                  // 32

    score_kernel<<<(int)(nrows / RPB), 256, 0, stream>>>(x, W, bias, score);
    sort_gather_kernel<<<B, 256, 0, stream>>>(score, x, out);
}